// Round 10
// baseline (101.888 us; speedup 1.0000x reference)
//
#include <hip/hip_runtime.h>
#include <math.h>

#define IMG 256
#define NFACE 1000
#define NFP 1024               // padded face count (per-wave 256, 4 rounds of 64)
#define NWAVE 4
#define NREP 7                 // measurement probe: repeat hot phases 7x
#define EPSF 1e-8f
#define LOG2E 1.44269504088896f
#define TCUT 16.0f             // drop contributions with u < -TCUT (<= 1.44*2^-16 each)
#define ACC_BREAK 25.0f        // once all lanes of a wave exceed: its tail < 2^-25
// Tile-center cull: max_tile u <= min_k c_k(center) + 3.5*sqrt(2)*LOG2E (=7.15)
#define CULL_M (-(TCUT + 7.15f))

// Static device scratch (graph-capture safe).
__device__ float g_soa[9][NFP];
__device__ float4 g_cf[NFP * 3];

// Opaque VGPR copy: defeats CSE between measurement reps without cost.
__device__ __forceinline__ float opq(float x) {
    asm volatile("" : "+v"(x));
    return x;
}

// ---------------------------------------------------------------------------
// Kernel 1: per-face edge line coefficients (log2e-scaled), SoA + AoS.
// Also zeroes out[] (block 0). Faces >= NFACE are self-rejecting pads.
// ---------------------------------------------------------------------------
__global__ __launch_bounds__(256) void k_coeff(const float* __restrict__ verts,
                                               const int* __restrict__ faces,
                                               const float* __restrict__ q,
                                               const float* __restrict__ t,
                                               const float* __restrict__ K,
                                               float* __restrict__ out) {
    int f = blockIdx.x * 256 + threadIdx.x;   // grid = 4 blocks -> f in [0,1024)
    if (blockIdx.x == 0 && threadIdx.x < IMG) out[threadIdx.x] = 0.f;
    if (f >= NFP) return;

    float c[9];
    if (f < NFACE) {
        float qw = q[0], qx = q[1], qy = q[2], qz = q[3];
        float qn = sqrtf(qw * qw + qx * qx + qy * qy + qz * qz + EPSF);
        qw /= qn; qx /= qn; qy /= qn; qz /= qn;
        float R00 = 1.f - 2.f * (qy * qy + qz * qz);
        float R01 = 2.f * (qx * qy - qw * qz);
        float R02 = 2.f * (qx * qz + qw * qy);
        float R10 = 2.f * (qx * qy + qw * qz);
        float R11 = 1.f - 2.f * (qx * qx + qz * qz);
        float R12 = 2.f * (qy * qz - qw * qx);
        float R20 = 2.f * (qx * qz - qw * qy);
        float R21 = 2.f * (qy * qz + qw * qx);
        float R22 = 1.f - 2.f * (qx * qx + qy * qy);
        float tx = t[0], ty = t[1], tz = t[2];
        float K00 = K[0], K02 = K[2], K11 = K[4], K12 = K[5];

        float X[3], Y[3];
#pragma unroll
        for (int k = 0; k < 3; ++k) {
            int vi = faces[f * 3 + k];
            float vx = verts[vi * 3 + 0];
            float vy = verts[vi * 3 + 1];
            float vz = verts[vi * 3 + 2];
            float cx = R00 * vx + R01 * vy + R02 * vz + tx;
            float cy = R10 * vx + R11 * vy + R12 * vz + ty;
            float cz = R20 * vx + R21 * vy + R22 * vz + tz;
            float z = cz + EPSF;
            X[k] = K00 * cx / z + K02;
            Y[k] = K11 * cy / z + K12;
        }

        float e01x = X[1] - X[0], e01y = Y[1] - Y[0];
        float e02x = X[2] - X[0], e02y = Y[2] - Y[0];
        float area2 = e01x * e02y - e01y * e02x;
        float s = (area2 >= 0.f) ? LOG2E : -LOG2E;

#pragma unroll
        for (int k = 0; k < 3; ++k) {
            int k1 = (k + 1) % 3;
            float ex = X[k1] - X[k];
            float ey = Y[k1] - Y[k];
            float inv = s / sqrtf(ex * ex + ey * ey + EPSF);
            c[k * 3 + 0] = -ey * inv;
            c[k * 3 + 1] = ex * inv;
            c[k * 3 + 2] = (ey * X[k] - ex * Y[k]) * inv;
        }
    } else {
        c[0] = 0.f; c[1] = 0.f; c[2] = -1e9f;
        c[3] = 0.f; c[4] = 0.f; c[5] = -1e9f;
        c[6] = 0.f; c[7] = 0.f; c[8] = -1e9f;
    }

#pragma unroll
    for (int k = 0; k < 9; ++k) g_soa[k][f] = c[k];
    g_cf[f * 3 + 0] = make_float4(c[0], c[1], c[2], 0.f);
    g_cf[f * 3 + 1] = make_float4(c[3], c[4], c[5], 0.f);
    g_cf[f * 3 + 2] = make_float4(c[6], c[7], c[8], 0.f);
}

// ---------------------------------------------------------------------------
// Kernel 2: fused render+loss. MEASUREMENT PROBE: the hot Phase A+B is run
// NREP times with opaque-laundered inputs (no CSE across reps); rep results
// are bitwise identical and combined via fmaxf (exact, keeps all reps live).
// Output remains exactly the R9 result; k_main duration scales ~NREP so it
// surfaces in rocprof top-5 with counters.
// ---------------------------------------------------------------------------
__global__ __launch_bounds__(256) void k_main(const float* __restrict__ image_ref,
                                              float* __restrict__ out) {
    const int tid = threadIdx.x;
    const int wave = tid >> 6;
    const int lane = tid & 63;
    const int x0 = blockIdx.x * 8, y0 = blockIdx.y * 8;
    const int col = x0 + (lane & 7);
    const int row = y0 + (lane >> 3);

    __shared__ __align__(8) short s_list[NWAVE][260];
    __shared__ float s_acc[NWAVE][64];

    float acc_keep = -1e30f;

    for (int rep = 0; rep < NREP; ++rep) {
        // opaque copies: each rep recomputes everything downstream
        const float px = opq(col + 0.5f);
        const float py = opq(row + 0.5f);
        const float tcx = opq(x0 + 4.0f);
        const float tcy = opq(y0 + 4.0f);

        // ---- Phase A: cull + compaction (4 rounds) ----
        const int wbase = wave * 256;
        int cnt = 0;
#pragma unroll
        for (int r = 0; r < 4; ++r) {
            int f = wbase + r * 64 + lane;
            float a0 = g_soa[0][f], a1 = g_soa[1][f], a2 = g_soa[2][f];
            float b0 = g_soa[3][f], b1 = g_soa[4][f], b2 = g_soa[5][f];
            float d0 = g_soa[6][f], d1 = g_soa[7][f], d2 = g_soa[8][f];
            float m = fminf(fminf(fmaf(tcx, a0, fmaf(tcy, a1, a2)),
                                  fmaf(tcx, b0, fmaf(tcy, b1, b2))),
                            fmaf(tcx, d0, fmaf(tcy, d1, d2)));
            bool hit = (m > CULL_M);
            unsigned long long msk = __ballot(hit);
            if (hit) {
                int pos = __popcll(msk & ((1ull << lane) - 1ull));
                s_list[wave][cnt + pos] = (short)f;
            }
            cnt += __popcll(msk);
        }
        int cntp = (cnt + 3) & ~3;
        if (lane < cntp - cnt) s_list[wave][cnt + lane] = (short)NFACE;

        // ---- Phase B: survivors, 4-face groups ----
        float acc = 0.f;
        for (int i = 0; i < cntp; i += 4) {
            short4 id = *(const short4*)&s_list[wave][i];
            const float4* pA = &g_cf[id.x * 3];
            const float4* pB = &g_cf[id.y * 3];
            const float4* pC = &g_cf[id.z * 3];
            const float4* pD = &g_cf[id.w * 3];
            float4 aA = pA[0], bA = pA[1], cA = pA[2];
            float4 aB = pB[0], bB = pB[1], cB = pB[2];
            float4 aC = pC[0], bC = pC[1], cC = pC[2];
            float4 aD = pD[0], bD = pD[1], cD = pD[2];
            float uA = fminf(fminf(fmaf(px, aA.x, fmaf(py, aA.y, aA.z)),
                                   fmaf(px, bA.x, fmaf(py, bA.y, bA.z))),
                             fmaf(px, cA.x, fmaf(py, cA.y, cA.z)));
            float uB = fminf(fminf(fmaf(px, aB.x, fmaf(py, aB.y, aB.z)),
                                   fmaf(px, bB.x, fmaf(py, bB.y, bB.z))),
                             fmaf(px, cB.x, fmaf(py, cB.y, cB.z)));
            float uC = fminf(fminf(fmaf(px, aC.x, fmaf(py, aC.y, aC.z)),
                                   fmaf(px, bC.x, fmaf(py, bC.y, bC.z))),
                             fmaf(px, cC.x, fmaf(py, cC.y, cC.z)));
            float uD = fminf(fminf(fmaf(px, aD.x, fmaf(py, aD.y, aD.z)),
                                   fmaf(px, bD.x, fmaf(py, bD.y, bD.z))),
                             fmaf(px, cD.x, fmaf(py, cD.y, cD.z)));
            acc += fmaxf(uA, 0.f) + fmaxf(uB, 0.f) + fmaxf(uC, 0.f) + fmaxf(uD, 0.f);
            acc += __builtin_amdgcn_logf(1.f + __builtin_amdgcn_exp2f(-fabsf(uA)));
            acc += __builtin_amdgcn_logf(1.f + __builtin_amdgcn_exp2f(-fabsf(uB)));
            acc += __builtin_amdgcn_logf(1.f + __builtin_amdgcn_exp2f(-fabsf(uC)));
            acc += __builtin_amdgcn_logf(1.f + __builtin_amdgcn_exp2f(-fabsf(uD)));
            if (__all(acc > ACC_BREAK)) break;
        }

        acc_keep = fmaxf(acc_keep, acc);  // identical values: exact, keeps reps live
    }

    // ---- combine waves, sil, sqdiff, row-reduce, atomic row partial ----
    s_acc[wave][lane] = acc_keep;
    __syncthreads();
    if (wave == 0) {
        float tot = s_acc[0][lane] + s_acc[1][lane] +
                    s_acc[2][lane] + s_acc[3][lane];
        float sil = 1.f - __builtin_amdgcn_exp2f(-tot);
        float d = sil - image_ref[row * IMG + col];
        float v = d * d;
        v += __shfl_xor(v, 1);
        v += __shfl_xor(v, 2);
        v += __shfl_xor(v, 4);
        if ((lane & 7) == 0) atomicAdd(&out[row], v * (1.f / 256.f));
    }
}

// ---------------------------------------------------------------------------
extern "C" void kernel_launch(void* const* d_in, const int* in_sizes, int n_in,
                              void* d_out, int out_size, void* d_ws, size_t ws_size,
                              hipStream_t stream) {
    const float* verts = (const float*)d_in[0];      // (1,1000,3) f32
    const int* faces = (const int*)d_in[1];          // (1,1000,3) i32
    const float* q = (const float*)d_in[2];          // (4,) f32
    const float* t = (const float*)d_in[3];          // (3,) f32
    const float* K = (const float*)d_in[4];          // (3,3) f32
    const float* image_ref = (const float*)d_in[5];  // (256,256) f32
    float* out = (float*)d_out;                      // (256,) f32

    k_coeff<<<NFP / 256, 256, 0, stream>>>(verts, faces, q, t, K, out);
    k_main<<<dim3(IMG / 8, IMG / 8), 256, 0, stream>>>(image_ref, out);
}

// Round 11
// 26.657 us; speedup vs baseline: 3.8222x; 3.8222x over previous
//
#include <hip/hip_runtime.h>
#include <math.h>

#define IMG 256
#define NFACE 1000
#define NFP 1024               // padded face count; 8 waves x 128 faces
#define NWAVE 8
#define FPW 128                // faces per wave (2 cull rounds of 64)
#define EPSF 1e-8f
#define LOG2E 1.44269504088896f
#define TCUT 16.0f             // drop contributions with u < -TCUT (<= 1.44*2^-16 each)
#define ACC_BREAK 25.0f        // once all lanes of a wave exceed: its tail < 2^-25
// Tile-center cull: max_tile u <= min_k c_k(center) + 3.5*sqrt(2)*LOG2E (=7.15)
#define CULL_M (-(TCUT + 7.15f))

// Static device scratch (graph-capture safe).
// SoA for the cull pass (coalesced dword loads), AoS float4 for the compute
// pass (uniform broadcast loads). log2e-scaled. Faces >= NFACE are
// self-rejecting pads (c0 = -1e9): never survive cull, contribute exactly 0
// when used as list-padding sentinels.
__device__ float g_soa[9][NFP];
__device__ float4 g_cf[NFP * 3];

// ---------------------------------------------------------------------------
// Kernel 1: per-face edge line coefficients (log2e-scaled), SoA + AoS.
// Also zeroes out[] (block 0) for k_main's atomic row accumulation.
// Degenerate faces (repeated vertex -> zero edge -> c==0 everywhere, face
// paints an infinite line band) need no special case under the center test.
// ---------------------------------------------------------------------------
__global__ __launch_bounds__(256) void k_coeff(const float* __restrict__ verts,
                                               const int* __restrict__ faces,
                                               const float* __restrict__ q,
                                               const float* __restrict__ t,
                                               const float* __restrict__ K,
                                               float* __restrict__ out) {
    int f = blockIdx.x * 256 + threadIdx.x;   // grid = 4 blocks -> f in [0,1024)
    if (blockIdx.x == 0 && threadIdx.x < IMG) out[threadIdx.x] = 0.f;
    if (f >= NFP) return;

    float c[9];
    if (f < NFACE) {
        float qw = q[0], qx = q[1], qy = q[2], qz = q[3];
        float qn = sqrtf(qw * qw + qx * qx + qy * qy + qz * qz + EPSF);
        qw /= qn; qx /= qn; qy /= qn; qz /= qn;
        float R00 = 1.f - 2.f * (qy * qy + qz * qz);
        float R01 = 2.f * (qx * qy - qw * qz);
        float R02 = 2.f * (qx * qz + qw * qy);
        float R10 = 2.f * (qx * qy + qw * qz);
        float R11 = 1.f - 2.f * (qx * qx + qz * qz);
        float R12 = 2.f * (qy * qz - qw * qx);
        float R20 = 2.f * (qx * qz - qw * qy);
        float R21 = 2.f * (qy * qz + qw * qx);
        float R22 = 1.f - 2.f * (qx * qx + qy * qy);
        float tx = t[0], ty = t[1], tz = t[2];
        float K00 = K[0], K02 = K[2], K11 = K[4], K12 = K[5];

        float X[3], Y[3];
#pragma unroll
        for (int k = 0; k < 3; ++k) {
            int vi = faces[f * 3 + k];
            float vx = verts[vi * 3 + 0];
            float vy = verts[vi * 3 + 1];
            float vz = verts[vi * 3 + 2];
            float cx = R00 * vx + R01 * vy + R02 * vz + tx;
            float cy = R10 * vx + R11 * vy + R12 * vz + ty;
            float cz = R20 * vx + R21 * vy + R22 * vz + tz;
            float z = cz + EPSF;
            X[k] = K00 * cx / z + K02;
            Y[k] = K11 * cy / z + K12;
        }

        float e01x = X[1] - X[0], e01y = Y[1] - Y[0];
        float e02x = X[2] - X[0], e02y = Y[2] - Y[0];
        float area2 = e01x * e02y - e01y * e02x;
        float s = (area2 >= 0.f) ? LOG2E : -LOG2E;

#pragma unroll
        for (int k = 0; k < 3; ++k) {
            int k1 = (k + 1) % 3;
            float ex = X[k1] - X[k];
            float ey = Y[k1] - Y[k];
            float inv = s / sqrtf(ex * ex + ey * ey + EPSF);
            c[k * 3 + 0] = -ey * inv;
            c[k * 3 + 1] = ex * inv;
            c[k * 3 + 2] = (ey * X[k] - ex * Y[k]) * inv;
        }
    } else {
        c[0] = 0.f; c[1] = 0.f; c[2] = -1e9f;
        c[3] = 0.f; c[4] = 0.f; c[5] = -1e9f;
        c[6] = 0.f; c[7] = 0.f; c[8] = -1e9f;
    }

#pragma unroll
    for (int k = 0; k < 9; ++k) g_soa[k][f] = c[k];
    g_cf[f * 3 + 0] = make_float4(c[0], c[1], c[2], 0.f);
    g_cf[f * 3 + 1] = make_float4(c[3], c[4], c[5], 0.f);
    g_cf[f * 3 + 2] = make_float4(c[6], c[7], c[8], 0.f);
}

// ---------------------------------------------------------------------------
// Kernel 2: fused render+loss, occupancy-first (R10 probe: 17% VALUBusy,
// 15% occupancy, 4 waves/SIMD -> latency-bound). Now 512-thread blocks,
// 8 waves x 128 faces each: 1024 blocks x 8 waves = 8192 waves = 100%
// static occupancy (2048 thr/CU); __launch_bounds__(512,8) caps VGPR at 64.
// Per wave: 2 cull rounds, ~6 survivors, ~3 two-face compute groups - the
// serial chain halves and 8-deep wave interleave hides the rest.
// ---------------------------------------------------------------------------
__global__ __launch_bounds__(512, 8) void k_main(const float* __restrict__ image_ref,
                                                 float* __restrict__ out) {
    const int tid = threadIdx.x;
    const int wave = tid >> 6;
    const int lane = tid & 63;
    const int x0 = blockIdx.x * 8, y0 = blockIdx.y * 8;
    const int col = x0 + (lane & 7);
    const int row = y0 + (lane >> 3);
    const float px = col + 0.5f;
    const float py = row + 0.5f;
    const float tcx = x0 + 4.0f;   // pixel centers span +0.5..+7.5
    const float tcy = y0 + 4.0f;

    __shared__ __align__(4) short s_list[NWAVE][132];
    __shared__ float s_acc[NWAVE][64];

    // ---- Phase A: cull + compaction (2 rounds, no bounds checks) ----
    const int wbase = wave * FPW;
    int cnt = 0;
#pragma unroll
    for (int r = 0; r < 2; ++r) {
        int f = wbase + r * 64 + lane;
        float a0 = g_soa[0][f], a1 = g_soa[1][f], a2 = g_soa[2][f];
        float b0 = g_soa[3][f], b1 = g_soa[4][f], b2 = g_soa[5][f];
        float d0 = g_soa[6][f], d1 = g_soa[7][f], d2 = g_soa[8][f];
        float m = fminf(fminf(fmaf(tcx, a0, fmaf(tcy, a1, a2)),
                              fmaf(tcx, b0, fmaf(tcy, b1, b2))),
                        fmaf(tcx, d0, fmaf(tcy, d1, d2)));
        bool hit = (m > CULL_M);
        unsigned long long msk = __ballot(hit);
        if (hit) {
            int pos = __popcll(msk & ((1ull << lane) - 1ull));
            s_list[wave][cnt + pos] = (short)f;
        }
        cnt += __popcll(msk);
    }
    // pad to a multiple of 2 with the zero-contribution sentinel
    int cntp = (cnt + 1) & ~1;
    if (cntp != cnt && lane == 0) s_list[wave][cnt] = (short)NFACE;

    // ---- Phase B: survivors, 2-face groups ----
    float acc = 0.f;
    for (int i = 0; i < cntp; i += 2) {
        short2 id = *(const short2*)&s_list[wave][i];
        const float4* pA = &g_cf[id.x * 3];
        const float4* pB = &g_cf[id.y * 3];
        float4 aA = pA[0], bA = pA[1], cA = pA[2];
        float4 aB = pB[0], bB = pB[1], cB = pB[2];
        float uA = fminf(fminf(fmaf(px, aA.x, fmaf(py, aA.y, aA.z)),
                               fmaf(px, bA.x, fmaf(py, bA.y, bA.z))),
                         fmaf(px, cA.x, fmaf(py, cA.y, cA.z)));
        float uB = fminf(fminf(fmaf(px, aB.x, fmaf(py, aB.y, aB.z)),
                               fmaf(px, bB.x, fmaf(py, bB.y, bB.z))),
                         fmaf(px, cB.x, fmaf(py, cB.y, cB.z)));
        acc += fmaxf(uA, 0.f) + fmaxf(uB, 0.f);
        acc += __builtin_amdgcn_logf(1.f + __builtin_amdgcn_exp2f(-fabsf(uA)));
        acc += __builtin_amdgcn_logf(1.f + __builtin_amdgcn_exp2f(-fabsf(uB)));
        if (__all(acc > ACC_BREAK)) break;   // wave's remaining tail < 2^-25
    }

    // ---- combine waves, sil, sqdiff, row-reduce, atomic row partial ----
    s_acc[wave][lane] = acc;
    __syncthreads();
    if (wave == 0) {
        float tot = 0.f;
#pragma unroll
        for (int w = 0; w < NWAVE; ++w) tot += s_acc[w][lane];
        float sil = 1.f - __builtin_amdgcn_exp2f(-tot);
        float d = sil - image_ref[row * IMG + col];
        float v = d * d;
        v += __shfl_xor(v, 1);   // sum over the 8 cols of this tile row
        v += __shfl_xor(v, 2);
        v += __shfl_xor(v, 4);
        if ((lane & 7) == 0) atomicAdd(&out[row], v * (1.f / 256.f));
    }
}

// ---------------------------------------------------------------------------
extern "C" void kernel_launch(void* const* d_in, const int* in_sizes, int n_in,
                              void* d_out, int out_size, void* d_ws, size_t ws_size,
                              hipStream_t stream) {
    const float* verts = (const float*)d_in[0];      // (1,1000,3) f32
    const int* faces = (const int*)d_in[1];          // (1,1000,3) i32
    const float* q = (const float*)d_in[2];          // (4,) f32
    const float* t = (const float*)d_in[3];          // (3,) f32
    const float* K = (const float*)d_in[4];          // (3,3) f32
    const float* image_ref = (const float*)d_in[5];  // (256,256) f32
    float* out = (float*)d_out;                      // (256,) f32

    k_coeff<<<NFP / 256, 256, 0, stream>>>(verts, faces, q, t, K, out);
    k_main<<<dim3(IMG / 8, IMG / 8), 512, 0, stream>>>(image_ref, out);
}

// Round 12
// 21.222 us; speedup vs baseline: 4.8011x; 1.2561x over previous
//
#include <hip/hip_runtime.h>
#include <math.h>

#define IMG 256
#define NFACE 1000
#define NFP 1024               // padded face count; 4 waves x 256 faces (4 rounds)
#define NWAVE 4
#define EPSF 1e-8f
#define LOG2E 1.44269504088896f
#define TCUT 16.0f             // drop contributions with u < -TCUT (<= 1.44*2^-16 each)
#define ACC_BREAK 25.0f        // once all lanes of a wave exceed: its tail < 2^-25
// Tile-center cull: max_tile u <= min_k c_k(center) + 3.5*sqrt(2)*LOG2E (=7.15)
#define CULL_M (-(TCUT + 7.15f))

// Static device scratch (graph-capture safe). SoA only: 9 arrays of 1024
// (coalesced dword loads in k_main). log2e-scaled. Faces >= NFACE are
// self-rejecting pads (c2 = -1e9 -> never survive the cull).
__device__ float g_soa[9][NFP];

// Broadcast lane s's register to all lanes (uniform s -> v_readlane -> SGPR).
__device__ __forceinline__ float bcast(float x, int s) {
    return __uint_as_float(__builtin_amdgcn_readlane(__float_as_uint(x), s));
}

// ---------------------------------------------------------------------------
// Kernel 1: per-face edge line coefficients (log2e-scaled), SoA.
// Also zeroes out[] (block 0) for k_main's atomic row accumulation.
// Degenerate faces (repeated vertex -> zero edge -> c==0 everywhere, face
// paints an infinite line band) need no special case under the center test.
// ---------------------------------------------------------------------------
__global__ __launch_bounds__(256) void k_coeff(const float* __restrict__ verts,
                                               const int* __restrict__ faces,
                                               const float* __restrict__ q,
                                               const float* __restrict__ t,
                                               const float* __restrict__ K,
                                               float* __restrict__ out) {
    int f = blockIdx.x * 256 + threadIdx.x;   // grid = 4 blocks -> f in [0,1024)
    if (blockIdx.x == 0 && threadIdx.x < IMG) out[threadIdx.x] = 0.f;
    if (f >= NFP) return;

    float c[9];
    if (f < NFACE) {
        float qw = q[0], qx = q[1], qy = q[2], qz = q[3];
        float qn = sqrtf(qw * qw + qx * qx + qy * qy + qz * qz + EPSF);
        qw /= qn; qx /= qn; qy /= qn; qz /= qn;
        float R00 = 1.f - 2.f * (qy * qy + qz * qz);
        float R01 = 2.f * (qx * qy - qw * qz);
        float R02 = 2.f * (qx * qz + qw * qy);
        float R10 = 2.f * (qx * qy + qw * qz);
        float R11 = 1.f - 2.f * (qx * qx + qz * qz);
        float R12 = 2.f * (qy * qz - qw * qx);
        float R20 = 2.f * (qx * qz - qw * qy);
        float R21 = 2.f * (qy * qz + qw * qx);
        float R22 = 1.f - 2.f * (qx * qx + qy * qy);
        float tx = t[0], ty = t[1], tz = t[2];
        float K00 = K[0], K02 = K[2], K11 = K[4], K12 = K[5];

        float X[3], Y[3];
#pragma unroll
        for (int k = 0; k < 3; ++k) {
            int vi = faces[f * 3 + k];
            float vx = verts[vi * 3 + 0];
            float vy = verts[vi * 3 + 1];
            float vz = verts[vi * 3 + 2];
            float cx = R00 * vx + R01 * vy + R02 * vz + tx;
            float cy = R10 * vx + R11 * vy + R12 * vz + ty;
            float cz = R20 * vx + R21 * vy + R22 * vz + tz;
            float z = cz + EPSF;
            X[k] = K00 * cx / z + K02;
            Y[k] = K11 * cy / z + K12;
        }

        float e01x = X[1] - X[0], e01y = Y[1] - Y[0];
        float e02x = X[2] - X[0], e02y = Y[2] - Y[0];
        float area2 = e01x * e02y - e01y * e02x;
        float s = (area2 >= 0.f) ? LOG2E : -LOG2E;

#pragma unroll
        for (int k = 0; k < 3; ++k) {
            int k1 = (k + 1) % 3;
            float ex = X[k1] - X[k];
            float ey = Y[k1] - Y[k];
            float inv = s / sqrtf(ex * ex + ey * ey + EPSF);
            c[k * 3 + 0] = -ey * inv;
            c[k * 3 + 1] = ex * inv;
            c[k * 3 + 2] = (ey * X[k] - ex * Y[k]) * inv;
        }
    } else {
        c[0] = 0.f; c[1] = 0.f; c[2] = -1e9f;
        c[3] = 0.f; c[4] = 0.f; c[5] = -1e9f;
        c[6] = 0.f; c[7] = 0.f; c[8] = -1e9f;
    }

#pragma unroll
    for (int k = 0; k < 9; ++k) g_soa[k][f] = c[k];
}

// ---------------------------------------------------------------------------
// Kernel 2: fused render+loss, register-broadcast Phase B (R11 post-mortem:
// the survivor loop's dependent memory chain - LDS index -> uniform global
// loads - was ~14 us and TLP-proof). Per 64-face round:
//   cull:   9 coalesced SoA loads -> min3 at tile center -> ballot
//   walk:   iterate set bits (uniform SALU); per survivor broadcast the
//           owning lane's 9 coefficient REGISTERS via v_readlane (no memory),
//           then ~12 VALU + 2 trans. Per-round __all(acc>25) break.
// Block = 8x8 px tile, 4 waves x 256 faces. No LDS except the combine buf.
// ---------------------------------------------------------------------------
__global__ __launch_bounds__(256) void k_main(const float* __restrict__ image_ref,
                                              float* __restrict__ out) {
    const int tid = threadIdx.x;
    const int wave = tid >> 6;
    const int lane = tid & 63;
    const int x0 = blockIdx.x * 8, y0 = blockIdx.y * 8;
    const int col = x0 + (lane & 7);
    const int row = y0 + (lane >> 3);
    const float px = col + 0.5f;
    const float py = row + 0.5f;
    const float tcx = x0 + 4.0f;   // pixel centers span +0.5..+7.5
    const float tcy = y0 + 4.0f;

    __shared__ float s_acc[NWAVE][64];

    float acc = 0.f;
    const int wbase = wave * 256;
    for (int r = 0; r < 4; ++r) {
        const int f = wbase + r * 64 + lane;
        float l0 = g_soa[0][f], l1 = g_soa[1][f], l2 = g_soa[2][f];
        float l3 = g_soa[3][f], l4 = g_soa[4][f], l5 = g_soa[5][f];
        float l6 = g_soa[6][f], l7 = g_soa[7][f], l8 = g_soa[8][f];
        float m = fminf(fminf(fmaf(tcx, l0, fmaf(tcy, l1, l2)),
                              fmaf(tcx, l3, fmaf(tcy, l4, l5))),
                        fmaf(tcx, l6, fmaf(tcy, l7, l8)));
        unsigned long long msk = __ballot(m > CULL_M);
        while (msk) {
            int s = __ffsll((unsigned long long)msk) - 1;  // uniform
            msk &= msk - 1;
            float a0 = bcast(l0, s), a1 = bcast(l1, s), a2 = bcast(l2, s);
            float b0 = bcast(l3, s), b1 = bcast(l4, s), b2 = bcast(l5, s);
            float c0 = bcast(l6, s), c1 = bcast(l7, s), c2 = bcast(l8, s);
            float u = fminf(fminf(fmaf(px, a0, fmaf(py, a1, a2)),
                                  fmaf(px, b0, fmaf(py, b1, b2))),
                            fmaf(px, c0, fmaf(py, c1, c2)));
            acc += fmaxf(u, 0.f);
            acc += __builtin_amdgcn_logf(1.f + __builtin_amdgcn_exp2f(-fabsf(u)));
        }
        if (__all(acc > ACC_BREAK)) break;   // wave's remaining tail < 2^-25
    }

    // ---- combine waves, sil, sqdiff, row-reduce, atomic row partial ----
    s_acc[wave][lane] = acc;
    __syncthreads();
    if (wave == 0) {
        float tot = s_acc[0][lane] + s_acc[1][lane] +
                    s_acc[2][lane] + s_acc[3][lane];
        float sil = 1.f - __builtin_amdgcn_exp2f(-tot);
        float d = sil - image_ref[row * IMG + col];
        float v = d * d;
        v += __shfl_xor(v, 1);   // sum over the 8 cols of this tile row
        v += __shfl_xor(v, 2);
        v += __shfl_xor(v, 4);
        if ((lane & 7) == 0) atomicAdd(&out[row], v * (1.f / 256.f));
    }
}

// ---------------------------------------------------------------------------
extern "C" void kernel_launch(void* const* d_in, const int* in_sizes, int n_in,
                              void* d_out, int out_size, void* d_ws, size_t ws_size,
                              hipStream_t stream) {
    const float* verts = (const float*)d_in[0];      // (1,1000,3) f32
    const int* faces = (const int*)d_in[1];          // (1,1000,3) i32
    const float* q = (const float*)d_in[2];          // (4,) f32
    const float* t = (const float*)d_in[3];          // (3,) f32
    const float* K = (const float*)d_in[4];          // (3,3) f32
    const float* image_ref = (const float*)d_in[5];  // (256,256) f32
    float* out = (float*)d_out;                      // (256,) f32

    k_coeff<<<NFP / 256, 256, 0, stream>>>(verts, faces, q, t, K, out);
    k_main<<<dim3(IMG / 8, IMG / 8), 256, 0, stream>>>(image_ref, out);
}